// Round 9
// baseline (197.067 us; speedup 1.0000x reference)
//
#include <hip/hip_runtime.h>
#include <hip/hip_bf16.h>
#include <math.h>

#define NH   16
#define NKV  4
#define HD   64
#define B_   2
#define T_   2048
#define C_   1024
#define QKVN 1536   // fused q(1024) | k(256) | v(256)

typedef __attribute__((ext_vector_type(8))) short short8;
typedef __attribute__((ext_vector_type(4))) float v4f;

__device__ inline ushort f2bf(float f) {
    union { float f; uint32_t u; } v; v.f = f;
    uint32_t r = v.u + 0x7fffu + ((v.u >> 16) & 1u);
    return (ushort)(r >> 16);
}

// pack two f32 -> one dword of bf16
__device__ inline uint pk_bf16(float a, float b) {
#if __has_builtin(__builtin_amdgcn_cvt_pk_bf16_f32)
    auto v = __builtin_amdgcn_cvt_pk_bf16_f32(a, b);
    union { decltype(v) v2; uint u; } cv; cv.v2 = v; return cv.u;
#else
    return (uint)f2bf(a) | ((uint)f2bf(b) << 16);
#endif
}

__device__ inline float ex2(float x) {
#if __has_builtin(__builtin_amdgcn_exp2f)
    return __builtin_amdgcn_exp2f(x);
#else
    return exp2f(x);
#endif
}

// async global->LDS, 16B per lane; LDS dest wave-uniform base + lane*16
__device__ inline void async16(const void* g, void* l) {
    __builtin_amdgcn_global_load_lds(
        (const __attribute__((address_space(1))) unsigned int*)g,
        (__attribute__((address_space(3))) unsigned int*)l, 16, 0, 0);
}

// ---------------- prep: x f32->bf16 convert + 4 weight transposes ----------
__global__ __launch_bounds__(256) void prep(
    const float* __restrict__ x,
    const float* __restrict__ Wq, const float* __restrict__ Wk,
    const float* __restrict__ Wv, const float* __restrict__ Wo,
    ushort* __restrict__ xb, ushort* __restrict__ WqkvT, ushort* __restrict__ WoT)
{
    const int bx = blockIdx.x;
    const int tid = threadIdx.x;
    if (bx < 640) {
        __shared__ float tile[64][65];
        const int cb = bx >> 4;
        const int kb = bx & 15;
        const float* src; ushort* dst; int N, nb;
        if (cb < 16)      { src = Wq; dst = WqkvT;                     N = 1024; nb = cb; }
        else if (cb < 20) { src = Wk; dst = WqkvT + (size_t)1024 * C_; N = 256;  nb = cb - 16; }
        else if (cb < 24) { src = Wv; dst = WqkvT + (size_t)1280 * C_; N = 256;  nb = cb - 20; }
        else              { src = Wo; dst = WoT;                       N = 1024; nb = cb - 24; }
        const int k0 = kb * 64, n0 = nb * 64;
        #pragma unroll
        for (int it = 0; it < 4; ++it) {
            int r = (tid >> 4) + it * 16;
            int c = (tid & 15) * 4;
            float4 v = *(const float4*)(src + (size_t)(k0 + r) * N + n0 + c);
            tile[r][c] = v.x; tile[r][c + 1] = v.y; tile[r][c + 2] = v.z; tile[r][c + 3] = v.w;
        }
        __syncthreads();
        #pragma unroll
        for (int it = 0; it < 4; ++it) {
            int r = (tid >> 4) + it * 16;
            int c = (tid & 15) * 4;
            ushort4 o;
            o.x = f2bf(tile[c + 0][r]); o.y = f2bf(tile[c + 1][r]);
            o.z = f2bf(tile[c + 2][r]); o.w = f2bf(tile[c + 3][r]);
            *(ushort4*)(dst + (size_t)(n0 + r) * C_ + k0 + c) = o;
        }
    } else {
        int i = ((bx - 640) * 256 + tid) * 4;   // covers 4096*1024 exactly
        float4 v = *(const float4*)(x + i);
        ushort4 o; o.x = f2bf(v.x); o.y = f2bf(v.y); o.z = f2bf(v.z); o.w = f2bf(v.w);
        *(ushort4*)(xb + i) = o;
    }
}

// ---------------- bf16 MFMA GEMM: C[M,N] = A[M,K] @ Bt[N,K]^T --------------
// R20 (proven, kept verbatim): BK=64 + XOR-swizzled LDS (conflict-free
// fragment reads), 16 barrier drains, 32 MFMA : 12 ds_read per iter,
// LDS 48KB -> 3 blocks/CU, single-raw-barrier + global_load_lds prefetch.
// ROPE path (QKV gemm): n0<1024 -> rope + 0.125*log2e scale (exp2 softmax);
// 1024..1279 -> rope only (k); n0>=1280 -> v stored transposed into vT.
template <bool BF16OUT, bool ROPE>
__global__ __launch_bounds__(256) void gemm_bf16bt(
    const ushort* __restrict__ A, const ushort* __restrict__ Bt,
    void* __restrict__ Cout, ushort* __restrict__ vTout,
    const float* __restrict__ cs, const float* __restrict__ sn,
    int M, int N, int K)
{
    __shared__ __align__(16) short As[2][128 * 64];   // rows of 64 shorts (128B)
    __shared__ __align__(16) short Bs[2][64 * 64];

    const int tid  = threadIdx.x;
    const int lane = tid & 63;
    const int wid  = tid >> 6;
    const int l16  = lane & 15;
    const int quad = lane >> 4;
    const int m0   = blockIdx.y * 128;
    const int n0   = blockIdx.x * 64;

    const int srow = lane >> 3;                   // 0..7 (8 lanes per 128B row)
    const int sblk = ((lane & 7) ^ srow) * 8;     // XOR-swizzled source col (shorts)

    // each async16 call stages 8 consecutive rows (64 lanes x 16B = 1KB)
    const ushort* agb = A  + (size_t)(m0 + wid * 32 + srow) * K + sblk;
    const ushort* bgb = Bt + (size_t)(n0 + wid * 16 + srow) * K + sblk;

    v4f acc[2][4];
    #pragma unroll
    for (int i = 0; i < 2; ++i)
        #pragma unroll
        for (int j = 0; j < 4; ++j) acc[i][j] = (v4f){0.f, 0.f, 0.f, 0.f};

    // prologue: stage iter 0 into buf 0 (A: 4 calls, B: 2 calls per wave)
    async16(agb,                  &As[0][(wid * 32     ) * 64]);
    async16(agb + (size_t) 8 * K, &As[0][(wid * 32 +  8) * 64]);
    async16(agb + (size_t)16 * K, &As[0][(wid * 32 + 16) * 64]);
    async16(agb + (size_t)24 * K, &As[0][(wid * 32 + 24) * 64]);
    async16(bgb,                  &Bs[0][(wid * 16     ) * 64]);
    async16(bgb + (size_t) 8 * K, &Bs[0][(wid * 16 +  8) * 64]);

    const int nIter = K >> 6;
    for (int it = 0; it < nIter; ++it) {
        // drain own buf-it DMAs (only thing in flight), publish to block.
        asm volatile("s_waitcnt vmcnt(0)\n\ts_barrier" ::: "memory");

        // prefetch iter it+1 into the other buffer; in flight across compute.
        if (it + 1 < nIter) {
            const int nb = (it + 1) & 1;
            const int k0 = (it + 1) << 6;
            async16(agb + k0,                  &As[nb][(wid * 32     ) * 64]);
            async16(agb + k0 + (size_t) 8 * K, &As[nb][(wid * 32 +  8) * 64]);
            async16(agb + k0 + (size_t)16 * K, &As[nb][(wid * 32 + 16) * 64]);
            async16(agb + k0 + (size_t)24 * K, &As[nb][(wid * 32 + 24) * 64]);
            async16(bgb + k0,                  &Bs[nb][(wid * 16     ) * 64]);
            async16(bgb + k0 + (size_t) 8 * K, &Bs[nb][(wid * 16 +  8) * 64]);
        }

        const short* Ab = As[it & 1];
        const short* Bb = Bs[it & 1];
        // fragment reads: row r holds global block b at slot b^(r&7).
        short8 af[2][2], bf[4][2];
        #pragma unroll
        for (int i = 0; i < 2; ++i)
            #pragma unroll
            for (int h = 0; h < 2; ++h)
                af[i][h] = *(const short8*)&Ab[(wid * 32 + i * 16 + l16) * 64 +
                                               ((((h << 2) + quad)) ^ (l16 & 7)) * 8];
        #pragma unroll
        for (int j = 0; j < 4; ++j)
            #pragma unroll
            for (int h = 0; h < 2; ++h)
                bf[j][h] = *(const short8*)&Bb[(j * 16 + l16) * 64 +
                                               ((((h << 2) + quad)) ^ (l16 & 7)) * 8];
        #pragma unroll
        for (int h = 0; h < 2; ++h)
            #pragma unroll
            for (int i = 0; i < 2; ++i)
                #pragma unroll
                for (int j = 0; j < 4; ++j)
                    acc[i][j] = __builtin_amdgcn_mfma_f32_16x16x32_bf16(af[i][h], bf[j][h], acc[i][j], 0, 0, 0);
    }

    if (ROPE && n0 >= 1280) {
        // v tile: store transposed to vT[(b*256 + (col-1280))][t]
        #pragma unroll
        for (int i = 0; i < 2; ++i) {
            const int row = m0 + wid * 32 + i * 16 + quad * 4;   // 4 consecutive t
            const int bb  = row >> 11;
            const int t   = row & (T_ - 1);
            #pragma unroll
            for (int j = 0; j < 4; ++j) {
                const int vc = n0 - 1280 + j * 16 + l16;
                ushort4 o;
                o.x = f2bf(acc[i][j][0]); o.y = f2bf(acc[i][j][1]);
                o.z = f2bf(acc[i][j][2]); o.w = f2bf(acc[i][j][3]);
                *(ushort4*)(vTout + (size_t)(bb * 256 + vc) * T_ + t) = o;
            }
        }
        return;
    }

    if (ROPE) {
        // q gets 0.125 * log2(e) so attention works in exp2 domain
        const float qs = (n0 < 1024) ? 0.18033688f : 1.0f;
        #pragma unroll
        for (int i = 0; i < 2; ++i) {
            #pragma unroll
            for (int r = 0; r < 4; ++r) {
                const int row = m0 + wid * 32 + i * 16 + quad * 4 + r;
                const int t = row & (T_ - 1);
                #pragma unroll
                for (int j = 0; j < 2; ++j) {
                    const int d = j * 16 + l16;
                    float cv = cs[t * 32 + d] * qs, sv = sn[t * 32 + d] * qs;
                    float x1 = acc[i][j][r], x2 = acc[i][j + 2][r];
                    acc[i][j][r]     = x1 * cv - x2 * sv;
                    acc[i][j + 2][r] = x2 * cv + x1 * sv;
                }
            }
        }
    }

    #pragma unroll
    for (int i = 0; i < 2; ++i) {
        #pragma unroll
        for (int r = 0; r < 4; ++r) {
            const int row = m0 + wid * 32 + i * 16 + quad * 4 + r;
            #pragma unroll
            for (int j = 0; j < 4; ++j) {
                const int col = n0 + j * 16 + l16;
                if (BF16OUT)
                    ((ushort*)Cout)[(size_t)row * N + col] = f2bf(acc[i][j][r]);
                else
                    ((float*)Cout)[(size_t)row * N + col] = acc[i][j][r];
            }
        }
    }
}

// ---------------- MFMA flash attention: 128-query tiles ------------------
// R21: q-tile 64 -> 128 (two 16-row halves per wave, sequential). Per
// chunk the K/V staging, both barriers and both DMA drains are UNCHANGED,
// but each wave now issues 64 MFMA instead of 32 — the fixed per-chunk
// sync cost (the measured bottleneck: MfmaUtil ~15%, all pipes idle) is
// amortized 2x. K/Vs/Ps layouts, swizzles, softmax (tree + defer-max +
// per-lane partial l), and the barrier protocol are byte-identical to R8.
// Ps is reused per half (pa0 is in registers before half-1 overwrites;
// per-wave DS ops are issue-ordered). Grid 1024 -> 512 single-tile blocks
// = ALL co-resident at 3 blocks/CU; heavy tiles (tb=15, nch=16) first;
// XCD swizzle kept.
#define PSTR 136
__global__ __launch_bounds__(256, 3) void attn_mfma(
    const ushort* __restrict__ qkv, const ushort* __restrict__ vT,
    ushort* __restrict__ y)
{
    __shared__ __align__(16) short Ks[128 * 64];      // [key][d] 128B rows
    __shared__ __align__(16) short Vs[64 * 128];      // [d][key] 256B rows
    __shared__ __align__(16) short Ps[4][16][PSTR];

    const int tid  = threadIdx.x;
    const int wid  = tid >> 6;
    const int ln   = tid & 63;
    const int l16  = ln & 15;
    const int quad = ln >> 4;

    const int bi   = blockIdx.x;          // 0..511
    const int xcd  = bi & 7;
    const int b    = xcd >> 2;
    const int kvh  = xcd & 3;
    const int jj   = bi >> 3;             // 0..63
    const int h    = kvh * 4 + (jj & 3);
    const int tb   = 15 - (jj >> 2);      // 0..15, heavy tiles first

    const ushort* kbase = qkv + (size_t)(b * T_) * QKVN + 1024 + kvh * HD;
    const ushort* vtb   = vT + (size_t)(b * 256 + kvh * HD) * T_;

    // K staging: wave stages rows r0..r0+31 (128B rows, 8 x16B blocks/row)
    const int r0   = wid * 32;
    const int srow = ln >> 3;                     // 0..7
    const int sblk = ((ln & 7) ^ srow) * 8;       // XOR-swizzled source col
    const int sl0  = (quad ^ (l16 & 7)) * 8;      // K frag slot, d-blocks 0..3
    const int sl1  = sl0 ^ 32;                    // d-blocks 4..7
    // V staging: wave stages d-rows vr0..vr0+15 (256B rows, 16 x16B blocks)
    const int vr0  = wid * 16;
    const int vrow = ln >> 4;                     // 0..3
    const int vs4  = ln & 15;                     // LDS slot within row

    const int q0  = tb * 128;
    const int nch = tb + 1;                   // 128-key chunks

    // Q B-fragments for both halves (pre-scaled by 0.125*log2e)
    short8 qa0, qa1, qb0, qb1;
    {
        const ushort* qrowA = qkv + (size_t)(b * T_ + q0 + wid * 16 + l16) * QKVN + h * HD;
        qa0 = *(const short8*)(qrowA + quad * 8);
        qa1 = *(const short8*)(qrowA + 32 + quad * 8);
        const ushort* qrowB = qrowA + (size_t)64 * QKVN;
        qb0 = *(const short8*)(qrowB + quad * 8);
        qb1 = *(const short8*)(qrowB + 32 + quad * 8);
    }

    v4f oa[4], ob[4];
    #pragma unroll
    for (int t = 0; t < 4; ++t) { oa[t] = (v4f){0.f,0.f,0.f,0.f}; ob[t] = (v4f){0.f,0.f,0.f,0.f}; }
    float ma = -1e30f, la = 0.f;   // per-lane PARTIAL l (this quad's keys)
    float mb = -1e30f, lb = 0.f;

    // prologue: stage K chunk 0
    {
        const ushort* kg = kbase + (size_t)(r0 + srow) * QKVN + sblk;
        async16(kg,                     &Ks[(r0     ) * 64]);
        async16(kg + (size_t) 8 * QKVN, &Ks[(r0 +  8) * 64]);
        async16(kg + (size_t)16 * QKVN, &Ks[(r0 + 16) * 64]);
        async16(kg + (size_t)24 * QKVN, &Ks[(r0 + 24) * 64]);
    }

    for (int c = 0; c < nch; ++c) {
        const int key0 = c * 128;

        // barrier A: own K chunk-c DMA is the only VMEM in flight; drain it
        // (+ lgkm so prev-chunk PV ds_reads are done before Vs overwrite),
        // then publish Ks to the block.
        asm volatile("s_waitcnt vmcnt(0) lgkmcnt(0)\n\ts_barrier" ::: "memory");

        // stage V chunk c into LDS; in flight across QK + softmax (x2).
        {
            const ushort* vg = vtb + (size_t)(vr0 + vrow) * T_ + key0;
            async16(vg                   + (vs4 ^ (vrow     )) * 8, &Vs[(vr0     ) * 128]);
            async16(vg + (size_t) 4 * T_ + (vs4 ^ (vrow +  4)) * 8, &Vs[(vr0 +  4) * 128]);
            async16(vg + (size_t) 8 * T_ + (vs4 ^ (vrow +  8)) * 8, &Vs[(vr0 +  8) * 128]);
            async16(vg + (size_t)12 * T_ + (vs4 ^ (vrow + 12)) * 8, &Vs[(vr0 + 12) * 128]);
        }

        const bool diag = (c == nch - 1);
        short8 pa0[4], pa1[4];

        // ================= half 0 (queries q0 + wid*16 + l16) =============
        {
            v4f st[8];
            __builtin_amdgcn_s_setprio(1);
            #pragma unroll
            for (int t = 0; t < 8; ++t) {
                short8 k0f = *(const short8*)&Ks[(t * 16 + l16) * 64 + sl0];
                short8 k1f = *(const short8*)&Ks[(t * 16 + l16) * 64 + sl1];
                v4f s = (v4f){0.f, 0.f, 0.f, 0.f};
                s = __builtin_amdgcn_mfma_f32_16x16x32_bf16(k0f, qa0, s, 0, 0, 0);
                s = __builtin_amdgcn_mfma_f32_16x16x32_bf16(k1f, qa1, s, 0, 0, 0);
                st[t] = s;
            }
            __builtin_amdgcn_s_setprio(0);

            if (diag) {
                const int qg = q0 + wid * 16 + l16;
                #pragma unroll
                for (int t = 0; t < 8; ++t)
                    #pragma unroll
                    for (int r = 0; r < 4; ++r)
                        if (key0 + t * 16 + quad * 4 + r > qg) st[t][r] = -1e30f;
            }

            float tm[8];
            #pragma unroll
            for (int t = 0; t < 8; ++t)
                tm[t] = fmaxf(fmaxf(st[t][0], st[t][1]), fmaxf(st[t][2], st[t][3]));
            float mx = fmaxf(fmaxf(fmaxf(tm[0], tm[1]), fmaxf(tm[2], tm[3])),
                             fmaxf(fmaxf(tm[4], tm[5]), fmaxf(tm[6], tm[7])));
            if (!__all(mx <= ma + 8.0f)) {
                float mf = fmaxf(mx, __shfl_xor(mx, 16, 64));
                mf = fmaxf(mf, __shfl_xor(mf, 32, 64));
                const float mnew  = fmaxf(ma, mf);
                const float alpha = ex2(ma - mnew);
                ma = mnew;
                la *= alpha;
                #pragma unroll
                for (int t = 0; t < 4; ++t)
                    #pragma unroll
                    for (int r = 0; r < 4; ++r) oa[t][r] *= alpha;
            }
            float ts[8];
            #pragma unroll
            for (int t = 0; t < 8; ++t) {
                st[t][0] = ex2(st[t][0] - ma); st[t][1] = ex2(st[t][1] - ma);
                st[t][2] = ex2(st[t][2] - ma); st[t][3] = ex2(st[t][3] - ma);
                ts[t] = (st[t][0] + st[t][1]) + (st[t][2] + st[t][3]);
            }
            la += ((ts[0] + ts[1]) + (ts[2] + ts[3])) +
                  ((ts[4] + ts[5]) + (ts[6] + ts[7]));

            #pragma unroll
            for (int t = 0; t < 8; ++t) {
                uint2 w;
                w.x = pk_bf16(st[t][0], st[t][1]);
                w.y = pk_bf16(st[t][2], st[t][3]);
                *(uint2*)&Ps[wid][l16][t * 16 + quad * 4] = w;
            }
            asm volatile("s_waitcnt lgkmcnt(0)" ::: "memory");
            #pragma unroll
            for (int seg = 0; seg < 4; ++seg)
                pa0[seg] = *(const short8*)&Ps[wid][l16][seg * 32 + quad * 8];
        }

        // ================= half 1 (queries +64) ===========================
        {
            v4f st[8];
            __builtin_amdgcn_s_setprio(1);
            #pragma unroll
            for (int t = 0; t < 8; ++t) {
                short8 k0f = *(const short8*)&Ks[(t * 16 + l16) * 64 + sl0];
                short8 k1f = *(const short8*)&Ks[(t * 16 + l16) * 64 + sl1];
                v4f s = (v4f){0.f, 0.f, 0.f, 0.f};
                s = __builtin_amdgcn_mfma_f32_16x16x32_bf16(k0f, qb0, s, 0, 0, 0);
                s = __builtin_amdgcn_mfma_f32_16x16x32_bf16(k1f, qb1, s, 0, 0, 0);
                st[t] = s;
            }
            __builtin_amdgcn_s_setprio(0);

            if (diag) {
                const int qg = q0 + 64 + wid * 16 + l16;
                #pragma unroll
                for (int t = 0; t < 8; ++t)
                    #pragma unroll
                    for (int r = 0; r < 4; ++r)
                        if (key0 + t * 16 + quad * 4 + r > qg) st[t][r] = -1e30f;
            }

            float tm[8];
            #pragma unroll
            for (int t = 0; t < 8; ++t)
                tm[t] = fmaxf(fmaxf(st[t][0], st[t][1]), fmaxf(st[t][2], st[t][3]));
            float mx = fmaxf(fmaxf(fmaxf(tm[0], tm[1]), fmaxf(tm[2], tm[3])),
                             fmaxf(fmaxf(tm[4], tm[5]), fmaxf(tm[6], tm[7])));
            if (!__all(mx <= mb + 8.0f)) {
                float mf = fmaxf(mx, __shfl_xor(mx, 16, 64));
                mf = fmaxf(mf, __shfl_xor(mf, 32, 64));
                const float mnew  = fmaxf(mb, mf);
                const float alpha = ex2(mb - mnew);
                mb = mnew;
                lb *= alpha;
                #pragma unroll
                for (int t = 0; t < 4; ++t)
                    #pragma unroll
                    for (int r = 0; r < 4; ++r) ob[t][r] *= alpha;
            }
            float ts[8];
            #pragma unroll
            for (int t = 0; t < 8; ++t) {
                st[t][0] = ex2(st[t][0] - mb); st[t][1] = ex2(st[t][1] - mb);
                st[t][2] = ex2(st[t][2] - mb); st[t][3] = ex2(st[t][3] - mb);
                ts[t] = (st[t][0] + st[t][1]) + (st[t][2] + st[t][3]);
            }
            lb += ((ts[0] + ts[1]) + (ts[2] + ts[3])) +
                  ((ts[4] + ts[5]) + (ts[6] + ts[7]));

            #pragma unroll
            for (int t = 0; t < 8; ++t) {
                uint2 w;
                w.x = pk_bf16(st[t][0], st[t][1]);
                w.y = pk_bf16(st[t][2], st[t][3]);
                *(uint2*)&Ps[wid][l16][t * 16 + quad * 4] = w;
            }
            asm volatile("s_waitcnt lgkmcnt(0)" ::: "memory");
            #pragma unroll
            for (int seg = 0; seg < 4; ++seg)
                pa1[seg] = *(const short8*)&Ps[wid][l16][seg * 32 + quad * 8];
        }

        // barrier B: V DMAs are the only VMEM in flight -> vmcnt(0) drains
        // them; s_barrier makes ALL waves' V rows visible.
        asm volatile("s_waitcnt vmcnt(0)\n\ts_barrier" ::: "memory");

        // issue K chunk c+1 into Ks (WAR-safe after barrier B); in flight
        // across both PV halves + loop-around.
        if (c + 1 < nch) {
            const ushort* kg = kbase + (size_t)(key0 + 128 + r0 + srow) * QKVN + sblk;
            async16(kg,                     &Ks[(r0     ) * 64]);
            async16(kg + (size_t) 8 * QKVN, &Ks[(r0 +  8) * 64]);
            async16(kg + (size_t)16 * QKVN, &Ks[(r0 + 16) * 64]);
            async16(kg + (size_t)24 * QKVN, &Ks[(r0 + 24) * 64]);
        }

        // ---- O^T += V^T @ P^T for both halves (V frags shared) ----
        __builtin_amdgcn_s_setprio(1);
        #pragma unroll
        for (int t = 0; t < 4; ++t) {
            const int dr = t * 16 + l16;          // V d-row
            #pragma unroll
            for (int seg = 0; seg < 4; ++seg) {
                const int slot = ((seg * 4 + quad) ^ dr) & 15;
                short8 vv = *(const short8*)&Vs[dr * 128 + slot * 8];
                oa[t] = __builtin_amdgcn_mfma_f32_16x16x32_bf16(vv, pa0[seg], oa[t], 0, 0, 0);
                ob[t] = __builtin_amdgcn_mfma_f32_16x16x32_bf16(vv, pa1[seg], ob[t], 0, 0, 0);
            }
        }
        __builtin_amdgcn_s_setprio(0);
    }

    // epilogue: cross-quad reduce partial l's, write both halves
    float lta = la + __shfl_xor(la, 16, 64);
    lta += __shfl_xor(lta, 32, 64);
    float ltb = lb + __shfl_xor(lb, 16, 64);
    ltb += __shfl_xor(ltb, 32, 64);
    const float inva = 1.0f / lta;
    const float invb = 1.0f / ltb;
    ushort* yrowA = y + (size_t)(b * T_ + q0 + wid * 16 + l16) * (NH * HD) + h * HD;
    ushort* yrowB = yrowA + (size_t)64 * (NH * HD);
    #pragma unroll
    for (int t = 0; t < 4; ++t) {
        ushort4 o;
        o.x = f2bf(oa[t][0] * inva); o.y = f2bf(oa[t][1] * inva);
        o.z = f2bf(oa[t][2] * inva); o.w = f2bf(oa[t][3] * inva);
        *(ushort4*)(yrowA + t * 16 + quad * 4) = o;
        ushort4 p;
        p.x = f2bf(ob[t][0] * invb); p.y = f2bf(ob[t][1] * invb);
        p.z = f2bf(ob[t][2] * invb); p.w = f2bf(ob[t][3] * invb);
        *(ushort4*)(yrowB + t * 16 + quad * 4) = p;
    }
}

// ---------------- launcher ----------------
extern "C" void kernel_launch(void* const* d_in, const int* in_sizes, int n_in,
                              void* d_out, int out_size, void* d_ws, size_t ws_size,
                              hipStream_t stream)
{
    const float* x    = (const float*)d_in[0];
    const float* cosT = (const float*)d_in[1];
    const float* sinT = (const float*)d_in[2];
    const float* Wq   = (const float*)d_in[3];
    const float* Wk   = (const float*)d_in[4];
    const float* Wv   = (const float*)d_in[5];
    const float* Wo   = (const float*)d_in[6];
    float* out = (float*)d_out;

    const int M = B_ * T_;  // 4096
    ushort* xb     = (ushort*)d_ws;                       // 4096*1024
    ushort* qkv    = xb  + (size_t)M * C_;                // 4096*1536
    ushort* yb     = qkv + (size_t)M * QKVN;              // 4096*1024
    ushort* WqkvT  = yb  + (size_t)M * C_;                // 1536*1024
    ushort* WoT    = WqkvT + (size_t)QKVN * C_;           // 1024*1024
    ushort* vTbuf  = WoT + (size_t)C_ * C_;               // 2*256*2048

    dim3 blk(256);
    // converts + weight transposes, one launch
    prep<<<640 + (M * C_) / 1024, blk, 0, stream>>>(x, Wq, Wk, Wv, Wo, xb, WqkvT, WoT);
    // fused QKV projection: rope(+exp2 scale) epilogue, v written straight to vT
    gemm_bf16bt<true, true><<<dim3(QKVN / 64, M / 128), blk, 0, stream>>>(
        xb, WqkvT, qkv, vTbuf, cosT, sinT, M, QKVN, C_);
    // attention (XCD-swizzled, 512 q128-tile blocks heavy-first, 3 blocks/CU)
    attn_mfma<<<512, blk, 0, stream>>>(qkv, vTbuf, yb);
    // output projection (fp32 out)
    gemm_bf16bt<false, false><<<dim3(C_ / 64, M / 128), blk, 0, stream>>>(
        yb, WoT, out, nullptr, nullptr, nullptr, M, C_, C_);
}

// Round 10
// 152.214 us; speedup vs baseline: 1.2947x; 1.2947x over previous
//
#include <hip/hip_runtime.h>
#include <hip/hip_bf16.h>
#include <math.h>

#define NH   16
#define NKV  4
#define HD   64
#define B_   2
#define T_   2048
#define C_   1024
#define QKVN 1536   // fused q(1024) | k(256) | v(256)

typedef __attribute__((ext_vector_type(8))) short short8;
typedef __attribute__((ext_vector_type(4))) float v4f;

__device__ inline ushort f2bf(float f) {
    union { float f; uint32_t u; } v; v.f = f;
    uint32_t r = v.u + 0x7fffu + ((v.u >> 16) & 1u);
    return (ushort)(r >> 16);
}

// pack two f32 -> one dword of bf16
__device__ inline uint pk_bf16(float a, float b) {
#if __has_builtin(__builtin_amdgcn_cvt_pk_bf16_f32)
    auto v = __builtin_amdgcn_cvt_pk_bf16_f32(a, b);
    union { decltype(v) v2; uint u; } cv; cv.v2 = v; return cv.u;
#else
    return (uint)f2bf(a) | ((uint)f2bf(b) << 16);
#endif
}

__device__ inline float ex2(float x) {
#if __has_builtin(__builtin_amdgcn_exp2f)
    return __builtin_amdgcn_exp2f(x);
#else
    return exp2f(x);
#endif
}

// async global->LDS, 16B per lane; LDS dest wave-uniform base + lane*16
__device__ inline void async16(const void* g, void* l) {
    __builtin_amdgcn_global_load_lds(
        (const __attribute__((address_space(1))) unsigned int*)g,
        (__attribute__((address_space(3))) unsigned int*)l, 16, 0, 0);
}

// ---------------- prep: x f32->bf16 convert + 4 weight transposes ----------
__global__ __launch_bounds__(256) void prep(
    const float* __restrict__ x,
    const float* __restrict__ Wq, const float* __restrict__ Wk,
    const float* __restrict__ Wv, const float* __restrict__ Wo,
    ushort* __restrict__ xb, ushort* __restrict__ WqkvT, ushort* __restrict__ WoT)
{
    const int bx = blockIdx.x;
    const int tid = threadIdx.x;
    if (bx < 640) {
        __shared__ float tile[64][65];
        const int cb = bx >> 4;
        const int kb = bx & 15;
        const float* src; ushort* dst; int N, nb;
        if (cb < 16)      { src = Wq; dst = WqkvT;                     N = 1024; nb = cb; }
        else if (cb < 20) { src = Wk; dst = WqkvT + (size_t)1024 * C_; N = 256;  nb = cb - 16; }
        else if (cb < 24) { src = Wv; dst = WqkvT + (size_t)1280 * C_; N = 256;  nb = cb - 20; }
        else              { src = Wo; dst = WoT;                       N = 1024; nb = cb - 24; }
        const int k0 = kb * 64, n0 = nb * 64;
        #pragma unroll
        for (int it = 0; it < 4; ++it) {
            int r = (tid >> 4) + it * 16;
            int c = (tid & 15) * 4;
            float4 v = *(const float4*)(src + (size_t)(k0 + r) * N + n0 + c);
            tile[r][c] = v.x; tile[r][c + 1] = v.y; tile[r][c + 2] = v.z; tile[r][c + 3] = v.w;
        }
        __syncthreads();
        #pragma unroll
        for (int it = 0; it < 4; ++it) {
            int r = (tid >> 4) + it * 16;
            int c = (tid & 15) * 4;
            ushort4 o;
            o.x = f2bf(tile[c + 0][r]); o.y = f2bf(tile[c + 1][r]);
            o.z = f2bf(tile[c + 2][r]); o.w = f2bf(tile[c + 3][r]);
            *(ushort4*)(dst + (size_t)(n0 + r) * C_ + k0 + c) = o;
        }
    } else {
        int i = ((bx - 640) * 256 + tid) * 4;   // covers 4096*1024 exactly
        float4 v = *(const float4*)(x + i);
        ushort4 o; o.x = f2bf(v.x); o.y = f2bf(v.y); o.z = f2bf(v.z); o.w = f2bf(v.w);
        *(ushort4*)(xb + i) = o;
    }
}

// ---------------- bf16 MFMA GEMM: C[M,N] = A[M,K] @ Bt[N,K]^T --------------
// R22 = R20 (proven: BK=64, XOR-swizzled conflict-free LDS reads, 16
// barrier drains, 3 blocks/CU) + T1 XCD-aware block swizzle: bijective
// bid remap (nwg%8==0 for both grids) gives each XCD a contiguous run of
// linear blocks = whole A row-bands pinned in that XCD's private L2.
// ROPE path (QKV gemm): n0<1024 -> rope + 0.125*log2e scale (exp2 softmax);
// 1024..1279 -> rope only (k); n0>=1280 -> v stored transposed into vT.
template <bool BF16OUT, bool ROPE>
__global__ __launch_bounds__(256) void gemm_bf16bt(
    const ushort* __restrict__ A, const ushort* __restrict__ Bt,
    void* __restrict__ Cout, ushort* __restrict__ vTout,
    const float* __restrict__ cs, const float* __restrict__ sn,
    int M, int N, int K)
{
    __shared__ __align__(16) short As[2][128 * 64];   // rows of 64 shorts (128B)
    __shared__ __align__(16) short Bs[2][64 * 64];

    const int tid  = threadIdx.x;
    const int lane = tid & 63;
    const int wid  = tid >> 6;
    const int l16  = lane & 15;
    const int quad = lane >> 4;

    // T1: XCD swizzle (bijective; nwg = 768 or 512, both %8==0).
    const int nx  = gridDim.x;
    const int nwg = nx * gridDim.y;
    int bid = blockIdx.y * nx + blockIdx.x;
    bid = (bid & 7) * (nwg >> 3) + (bid >> 3);
    const int m0 = (bid / nx) * 128;
    const int n0 = (bid % nx) * 64;

    const int srow = lane >> 3;                   // 0..7 (8 lanes per 128B row)
    const int sblk = ((lane & 7) ^ srow) * 8;     // XOR-swizzled source col (shorts)

    // each async16 call stages 8 consecutive rows (64 lanes x 16B = 1KB)
    const ushort* agb = A  + (size_t)(m0 + wid * 32 + srow) * K + sblk;
    const ushort* bgb = Bt + (size_t)(n0 + wid * 16 + srow) * K + sblk;

    v4f acc[2][4];
    #pragma unroll
    for (int i = 0; i < 2; ++i)
        #pragma unroll
        for (int j = 0; j < 4; ++j) acc[i][j] = (v4f){0.f, 0.f, 0.f, 0.f};

    // prologue: stage iter 0 into buf 0 (A: 4 calls, B: 2 calls per wave)
    async16(agb,                  &As[0][(wid * 32     ) * 64]);
    async16(agb + (size_t) 8 * K, &As[0][(wid * 32 +  8) * 64]);
    async16(agb + (size_t)16 * K, &As[0][(wid * 32 + 16) * 64]);
    async16(agb + (size_t)24 * K, &As[0][(wid * 32 + 24) * 64]);
    async16(bgb,                  &Bs[0][(wid * 16     ) * 64]);
    async16(bgb + (size_t) 8 * K, &Bs[0][(wid * 16 +  8) * 64]);

    const int nIter = K >> 6;
    for (int it = 0; it < nIter; ++it) {
        // drain own buf-it DMAs (only thing in flight), publish to block.
        asm volatile("s_waitcnt vmcnt(0)\n\ts_barrier" ::: "memory");

        // prefetch iter it+1 into the other buffer; in flight across compute.
        if (it + 1 < nIter) {
            const int nb = (it + 1) & 1;
            const int k0 = (it + 1) << 6;
            async16(agb + k0,                  &As[nb][(wid * 32     ) * 64]);
            async16(agb + k0 + (size_t) 8 * K, &As[nb][(wid * 32 +  8) * 64]);
            async16(agb + k0 + (size_t)16 * K, &As[nb][(wid * 32 + 16) * 64]);
            async16(agb + k0 + (size_t)24 * K, &As[nb][(wid * 32 + 24) * 64]);
            async16(bgb + k0,                  &Bs[nb][(wid * 16     ) * 64]);
            async16(bgb + k0 + (size_t) 8 * K, &Bs[nb][(wid * 16 +  8) * 64]);
        }

        const short* Ab = As[it & 1];
        const short* Bb = Bs[it & 1];
        // fragment reads: row r holds global block b at slot b^(r&7).
        short8 af[2][2], bf[4][2];
        #pragma unroll
        for (int i = 0; i < 2; ++i)
            #pragma unroll
            for (int h = 0; h < 2; ++h)
                af[i][h] = *(const short8*)&Ab[(wid * 32 + i * 16 + l16) * 64 +
                                               ((((h << 2) + quad)) ^ (l16 & 7)) * 8];
        #pragma unroll
        for (int j = 0; j < 4; ++j)
            #pragma unroll
            for (int h = 0; h < 2; ++h)
                bf[j][h] = *(const short8*)&Bb[(j * 16 + l16) * 64 +
                                               ((((h << 2) + quad)) ^ (l16 & 7)) * 8];
        #pragma unroll
        for (int h = 0; h < 2; ++h)
            #pragma unroll
            for (int i = 0; i < 2; ++i)
                #pragma unroll
                for (int j = 0; j < 4; ++j)
                    acc[i][j] = __builtin_amdgcn_mfma_f32_16x16x32_bf16(af[i][h], bf[j][h], acc[i][j], 0, 0, 0);
    }

    if (ROPE && n0 >= 1280) {
        // v tile: store transposed to vT[(b*256 + (col-1280))][t]
        #pragma unroll
        for (int i = 0; i < 2; ++i) {
            const int row = m0 + wid * 32 + i * 16 + quad * 4;   // 4 consecutive t
            const int bb  = row >> 11;
            const int t   = row & (T_ - 1);
            #pragma unroll
            for (int j = 0; j < 4; ++j) {
                const int vc = n0 - 1280 + j * 16 + l16;
                ushort4 o;
                o.x = f2bf(acc[i][j][0]); o.y = f2bf(acc[i][j][1]);
                o.z = f2bf(acc[i][j][2]); o.w = f2bf(acc[i][j][3]);
                *(ushort4*)(vTout + (size_t)(bb * 256 + vc) * T_ + t) = o;
            }
        }
        return;
    }

    if (ROPE) {
        // q gets 0.125 * log2(e) so attention works in exp2 domain
        const float qs = (n0 < 1024) ? 0.18033688f : 1.0f;
        #pragma unroll
        for (int i = 0; i < 2; ++i) {
            #pragma unroll
            for (int r = 0; r < 4; ++r) {
                const int row = m0 + wid * 32 + i * 16 + quad * 4 + r;
                const int t = row & (T_ - 1);
                #pragma unroll
                for (int j = 0; j < 2; ++j) {
                    const int d = j * 16 + l16;
                    float cv = cs[t * 32 + d] * qs, sv = sn[t * 32 + d] * qs;
                    float x1 = acc[i][j][r], x2 = acc[i][j + 2][r];
                    acc[i][j][r]     = x1 * cv - x2 * sv;
                    acc[i][j + 2][r] = x2 * cv + x1 * sv;
                }
            }
        }
    }

    #pragma unroll
    for (int i = 0; i < 2; ++i) {
        #pragma unroll
        for (int r = 0; r < 4; ++r) {
            const int row = m0 + wid * 32 + i * 16 + quad * 4 + r;
            #pragma unroll
            for (int j = 0; j < 4; ++j) {
                const int col = n0 + j * 16 + l16;
                if (BF16OUT)
                    ((ushort*)Cout)[(size_t)row * N + col] = f2bf(acc[i][j][r]);
                else
                    ((float*)Cout)[(size_t)row * N + col] = acc[i][j][r];
            }
        }
    }
}

// ---------------- MFMA flash attention: 128-key chunks -------------------
// R22: verbatim R8 revert (proven best: attn below the 44us fills).
// R9's 128-query widening spilled ~19MB/dispatch to scratch (WRITE_SIZE
// 8->27MB) and halved effective occupancy (grid 512, no backfill, uneven
// nch) — both structural; reverted. This version: 3 blocks/CU via
// single-buffered K, LDS-staged V and P, 2 barriers/chunk, K prefetch
// issued after barrier B with the whole PV + loop to land, grid 1024
// single 64-q-tile blocks heavy-first, XCD swizzle.
#define PSTR 136
__global__ __launch_bounds__(256, 3) void attn_mfma(
    const ushort* __restrict__ qkv, const ushort* __restrict__ vT,
    ushort* __restrict__ y)
{
    __shared__ __align__(16) short Ks[128 * 64];      // [key][d] 128B rows
    __shared__ __align__(16) short Vs[64 * 128];      // [d][key] 256B rows
    __shared__ __align__(16) short Ps[4][16][PSTR];

    const int tid  = threadIdx.x;
    const int wid  = tid >> 6;
    const int ln   = tid & 63;
    const int l16  = ln & 15;
    const int quad = ln >> 4;

    const int bi   = blockIdx.x;          // 0..1023
    const int xcd  = bi & 7;
    const int b    = xcd >> 2;
    const int kvh  = xcd & 3;
    const int jj   = bi >> 3;             // 0..127
    const int h    = kvh * 4 + (jj & 3);
    const int tb   = 31 - (jj >> 2);      // heavy tiles first

    const ushort* kbase = qkv + (size_t)(b * T_) * QKVN + 1024 + kvh * HD;
    const ushort* vtb   = vT + (size_t)(b * 256 + kvh * HD) * T_;

    // K staging: wave stages rows r0..r0+31 (128B rows, 8 x16B blocks/row)
    const int r0   = wid * 32;
    const int srow = ln >> 3;                     // 0..7
    const int sblk = ((ln & 7) ^ srow) * 8;       // XOR-swizzled source col
    const int sl0  = (quad ^ (l16 & 7)) * 8;      // K frag slot, d-blocks 0..3
    const int sl1  = sl0 ^ 32;                    // d-blocks 4..7
    // V staging: wave stages d-rows vr0..vr0+15 (256B rows, 16 x16B blocks)
    const int vr0  = wid * 16;
    const int vrow = ln >> 4;                     // 0..3
    const int vs4  = ln & 15;                     // LDS slot within row

    const int q0  = tb * 64;
    const int nch = tb / 2 + 1;               // 128-key chunks

    // Q B-fragments (pre-scaled by 0.125*log2e): B[n=l16][k=quad*8+j]
    short8 qf0, qf1;
    {
        const ushort* qrow = qkv + (size_t)(b * T_ + q0 + wid * 16 + l16) * QKVN + h * HD;
        qf0 = *(const short8*)(qrow + quad * 8);
        qf1 = *(const short8*)(qrow + 32 + quad * 8);
    }

    v4f oacc[4];
    #pragma unroll
    for (int t = 0; t < 4; ++t) oacc[t] = (v4f){0.f, 0.f, 0.f, 0.f};
    float m = -1e30f, l = 0.f;   // l: per-lane PARTIAL (this quad's keys)

    // prologue: stage K chunk 0
    {
        const ushort* kg = kbase + (size_t)(r0 + srow) * QKVN + sblk;
        async16(kg,                     &Ks[(r0     ) * 64]);
        async16(kg + (size_t) 8 * QKVN, &Ks[(r0 +  8) * 64]);
        async16(kg + (size_t)16 * QKVN, &Ks[(r0 + 16) * 64]);
        async16(kg + (size_t)24 * QKVN, &Ks[(r0 + 24) * 64]);
    }

    for (int c = 0; c < nch; ++c) {
        const int key0 = c * 128;

        // barrier A: own K chunk-c DMA is the only VMEM in flight; drain it
        // (+ lgkm so prev-chunk PV ds_reads are done before Vs overwrite),
        // then publish Ks to the block.
        asm volatile("s_waitcnt vmcnt(0) lgkmcnt(0)\n\ts_barrier" ::: "memory");

        // stage V chunk c into LDS; in flight across QK + softmax.
        // Swizzle: slot vs4 of d-row d holds global key-block vs4 ^ (d&15).
        {
            const ushort* vg = vtb + (size_t)(vr0 + vrow) * T_ + key0;
            async16(vg                   + (vs4 ^ (vrow     )) * 8, &Vs[(vr0     ) * 128]);
            async16(vg + (size_t) 4 * T_ + (vs4 ^ (vrow +  4)) * 8, &Vs[(vr0 +  4) * 128]);
            async16(vg + (size_t) 8 * T_ + (vs4 ^ (vrow +  8)) * 8, &Vs[(vr0 +  8) * 128]);
            async16(vg + (size_t)12 * T_ + (vs4 ^ (vrow + 12)) * 8, &Vs[(vr0 + 12) * 128]);
        }

        // ---- S^T = K @ Q^T (row=key, col=query), 8 key-tiles ----
        v4f st[8];
        __builtin_amdgcn_s_setprio(1);
        #pragma unroll
        for (int t = 0; t < 8; ++t) {
            short8 k0f = *(const short8*)&Ks[(t * 16 + l16) * 64 + sl0];
            short8 k1f = *(const short8*)&Ks[(t * 16 + l16) * 64 + sl1];
            v4f s = (v4f){0.f, 0.f, 0.f, 0.f};
            s = __builtin_amdgcn_mfma_f32_16x16x32_bf16(k0f, qf0, s, 0, 0, 0);
            s = __builtin_amdgcn_mfma_f32_16x16x32_bf16(k1f, qf1, s, 0, 0, 0);
            st[t] = s;
        }
        __builtin_amdgcn_s_setprio(0);

        // causal mask: only the chunk containing the diagonal
        if (c == nch - 1) {
            const int qg = wid * 16 + l16 + q0;
            #pragma unroll
            for (int t = 0; t < 8; ++t)
                #pragma unroll
                for (int r = 0; r < 4; ++r)
                    if (key0 + t * 16 + quad * 4 + r > qg) st[t][r] = -1e30f;
        }

        // ---- online softmax (exp2 domain), tree-reduced, defer-max ----
        float tm[8];
        #pragma unroll
        for (int t = 0; t < 8; ++t)
            tm[t] = fmaxf(fmaxf(st[t][0], st[t][1]), fmaxf(st[t][2], st[t][3]));
        float mx = fmaxf(fmaxf(fmaxf(tm[0], tm[1]), fmaxf(tm[2], tm[3])),
                         fmaxf(fmaxf(tm[4], tm[5]), fmaxf(tm[6], tm[7])));
        // common path: max grew by <= 8 for every lane -> keep old m,
        // skip cross-quad shfls and the whole rescale pass.
        if (!__all(mx <= m + 8.0f)) {
            float mf = fmaxf(mx, __shfl_xor(mx, 16, 64));
            mf = fmaxf(mf, __shfl_xor(mf, 32, 64));
            const float mnew  = fmaxf(m, mf);
            const float alpha = ex2(m - mnew);
            m = mnew;
            l *= alpha;
            #pragma unroll
            for (int t = 0; t < 4; ++t)
                #pragma unroll
                for (int r = 0; r < 4; ++r) oacc[t][r] *= alpha;
        }
        float p[8][4], ts[8];
        #pragma unroll
        for (int t = 0; t < 8; ++t) {
            p[t][0] = ex2(st[t][0] - m); p[t][1] = ex2(st[t][1] - m);
            p[t][2] = ex2(st[t][2] - m); p[t][3] = ex2(st[t][3] - m);
            ts[t] = (p[t][0] + p[t][1]) + (p[t][2] + p[t][3]);
        }
        l += ((ts[0] + ts[1]) + (ts[2] + ts[3])) +
             ((ts[4] + ts[5]) + (ts[6] + ts[7]));

        // write P^T rows: Ps[query=l16][key], packed pairs -> b64
        #pragma unroll
        for (int t = 0; t < 8; ++t) {
            uint2 w;
            w.x = pk_bf16(p[t][0], p[t][1]);
            w.y = pk_bf16(p[t][2], p[t][3]);
            *(uint2*)&Ps[wid][l16][t * 16 + quad * 4] = w;
        }

        // drain this wave's P ds_writes, read own P fragments (per-wave
        // scratch -> no barrier needed)
        asm volatile("s_waitcnt lgkmcnt(0)" ::: "memory");
        short8 pa[4];
        #pragma unroll
        for (int seg = 0; seg < 4; ++seg)
            pa[seg] = *(const short8*)&Ps[wid][l16][seg * 32 + quad * 8];

        // barrier B: V DMAs are the only VMEM in flight -> vmcnt(0) drains
        // them; s_barrier makes ALL waves' V rows visible. All waves are
        // past their Ks reads here (lgkm drained above), so Ks is free.
        asm volatile("s_waitcnt vmcnt(0)\n\ts_barrier" ::: "memory");

        // issue K chunk c+1 into Ks (WAR-safe after barrier B); in flight
        // across PV + loop-around, drained at the next barrier A.
        if (c + 1 < nch) {
            const ushort* kg = kbase + (size_t)(key0 + 128 + r0 + srow) * QKVN + sblk;
            async16(kg,                     &Ks[(r0     ) * 64]);
            async16(kg + (size_t) 8 * QKVN, &Ks[(r0 +  8) * 64]);
            async16(kg + (size_t)16 * QKVN, &Ks[(r0 + 16) * 64]);
            async16(kg + (size_t)24 * QKVN, &Ks[(r0 + 24) * 64]);
        }

        // ---- O^T += V^T @ P^T : V frags from LDS (swizzled rows) ----
        __builtin_amdgcn_s_setprio(1);
        #pragma unroll
        for (int t = 0; t < 4; ++t) {
            const int dr = t * 16 + l16;          // V d-row
            #pragma unroll
            for (int seg = 0; seg < 4; ++seg) {
                const int slot = ((seg * 4 + quad) ^ dr) & 15;
                short8 vv = *(const short8*)&Vs[dr * 128 + slot * 8];
                oacc[t] = __builtin_amdgcn_mfma_f32_16x16x32_bf16(vv, pa[seg], oacc[t], 0, 0, 0);
            }
        }
        __builtin_amdgcn_s_setprio(0);
    }

    // epilogue: cross-quad reduce the partial l, then y = O^T / l
    float lt = l + __shfl_xor(l, 16, 64);
    lt += __shfl_xor(lt, 32, 64);
    const float inv = 1.0f / lt;
    ushort* yrow = y + (size_t)(b * T_ + q0 + wid * 16 + l16) * (NH * HD) + h * HD;
    #pragma unroll
    for (int t = 0; t < 4; ++t) {
        ushort4 o;
        o.x = f2bf(oacc[t][0] * inv); o.y = f2bf(oacc[t][1] * inv);
        o.z = f2bf(oacc[t][2] * inv); o.w = f2bf(oacc[t][3] * inv);
        *(ushort4*)(yrow + t * 16 + quad * 4) = o;
    }
}

// ---------------- launcher ----------------
extern "C" void kernel_launch(void* const* d_in, const int* in_sizes, int n_in,
                              void* d_out, int out_size, void* d_ws, size_t ws_size,
                              hipStream_t stream)
{
    const float* x    = (const float*)d_in[0];
    const float* cosT = (const float*)d_in[1];
    const float* sinT = (const float*)d_in[2];
    const float* Wq   = (const float*)d_in[3];
    const float* Wk   = (const float*)d_in[4];
    const float* Wv   = (const float*)d_in[5];
    const float* Wo   = (const float*)d_in[6];
    float* out = (float*)d_out;

    const int M = B_ * T_;  // 4096
    ushort* xb     = (ushort*)d_ws;                       // 4096*1024
    ushort* qkv    = xb  + (size_t)M * C_;                // 4096*1536
    ushort* yb     = qkv + (size_t)M * QKVN;              // 4096*1024
    ushort* WqkvT  = yb  + (size_t)M * C_;                // 1536*1024
    ushort* WoT    = WqkvT + (size_t)QKVN * C_;           // 1024*1024
    ushort* vTbuf  = WoT + (size_t)C_ * C_;               // 2*256*2048

    dim3 blk(256);
    // converts + weight transposes, one launch
    prep<<<640 + (M * C_) / 1024, blk, 0, stream>>>(x, Wq, Wk, Wv, Wo, xb, WqkvT, WoT);
    // fused QKV projection: rope(+exp2 scale) epilogue, v written straight to vT
    gemm_bf16bt<true, true><<<dim3(QKVN / 64, M / 128), blk, 0, stream>>>(
        xb, WqkvT, qkv, vTbuf, cosT, sinT, M, QKVN, C_);
    // attention (XCD-swizzled, 1024 single-tile blocks heavy-first,
    // single-buffer K, 3 blocks/CU)
    attn_mfma<<<1024, blk, 0, stream>>>(qkv, vTbuf, yb);
    // output projection (fp32 out)
    gemm_bf16bt<false, false><<<dim3(C_ / 64, M / 128), blk, 0, stream>>>(
        yb, WoT, out, nullptr, nullptr, nullptr, M, C_, C_);
}